// Round 11
// baseline (457.584 us; speedup 1.0000x reference)
//
#include <hip/hip_runtime.h>

// ---------------------------------------------------------------------------
// Fused attention: x@Wqkv^T -> RoPE -> masked softmax attention -> @Wproj^T+b
// B=2, N=2048, C=1024, H=16, D=64.  All MFMA compute in bf16, fp32 accum.
//
// LESSON (R5):  no scalar 2B global stores — 16x HBM write amplification.
//               Fused epilogues must bounce through LDS to dense 16B stores.
// LESSON (R3):  direct-global loads feeding the chain HEAD expose L2 latency.
// LESSON (R7):  shrinking q-tiles duplicates staging; widen waves instead.
// LESSON (R9):  vmcnt is ordered; direct loads + DMA prefetch interact badly.
// LESSON (R10): V-direct from global loses even with correct ordering — 8
//               waves x redundant 16B loads swamp L1; all-LDS dbuf (R8 shape,
//               73 us measured) is the flash optimum.  Stop relitigating.
// ---------------------------------------------------------------------------

typedef __attribute__((ext_vector_type(8))) short          s16x8;
typedef __attribute__((ext_vector_type(8))) unsigned short u16x8;
typedef __attribute__((ext_vector_type(4))) unsigned short u16x4;
typedef __attribute__((ext_vector_type(4))) float          f32x4;

#define MFMA_BF16(a, b, c) __builtin_amdgcn_mfma_f32_16x16x32_bf16((a), (b), (c), 0, 0, 0)

// async global->LDS, 16B per lane (dest = wave-uniform base + lane*16)
#define GLD_TO_LDS(gp, lp) __builtin_amdgcn_global_load_lds(                  \
    (const __attribute__((address_space(1))) void*)(gp),                      \
    (__attribute__((address_space(3))) void*)(lp), 16, 0, 0)

__device__ __forceinline__ unsigned short f2bf(float f) {
    union { float f; unsigned int u; } v; v.f = f;
    unsigned int u = v.u;
    unsigned int r = u + 0x7FFFu + ((u >> 16) & 1u);   // round-to-nearest-even
    return (unsigned short)(r >> 16);
}

// ---------------------------------------------------------------------------
// prep: fp32->bf16 converts for x, w_qkv, w_proj + mask->float bias.
// [0,4096) x, [4096,7168) w_qkv, [7168,8192) w_proj, [8192,8208) mask.
// ---------------------------------------------------------------------------
__global__ __launch_bounds__(256) void prep(const float* __restrict__ x,
                                            const float* __restrict__ wqkv,
                                            const float* __restrict__ wproj,
                                            const int* __restrict__ m,
                                            unsigned short* __restrict__ xb,
                                            unsigned short* __restrict__ wqkvb,
                                            unsigned short* __restrict__ wprojb,
                                            float* __restrict__ fb) {
    int blk = blockIdx.x, tid = threadIdx.x;
    if (blk < 8192) {
        const float* src; unsigned short* dst; int i;
        if (blk < 4096)      { src = x;     dst = xb;     i = blk * 256 + tid; }
        else if (blk < 7168) { src = wqkv;  dst = wqkvb;  i = (blk - 4096) * 256 + tid; }
        else                 { src = wproj; dst = wprojb; i = (blk - 7168) * 256 + tid; }
        f32x4 v = ((const f32x4*)src)[i];
        u16x4 o;
        o[0] = f2bf(v[0]); o[1] = f2bf(v[1]); o[2] = f2bf(v[2]); o[3] = f2bf(v[3]);
        ((u16x4*)dst)[i] = o;
    } else {
        int i = (blk - 8192) * 256 + tid;
        fb[i] = (m[i] == 0) ? -1e5f : 0.0f;
    }
}

// ---------------------------------------------------------------------------
// QKV GEMM + fused RoPE/scatter.  qkv[128-row x 128-col] tile per block;
// each 128-col tile is entirely q, k, or v and spans exactly 2 heads.
// RoPE applied in-register on fp32 acc (pair = acc[i][j^2][r], same lane —
// math verified in R5).  Output goes through per-wave 64x72 LDS bounce
// buffers, then DENSE lane-consecutive u16x8 stores (R5 lesson):
//   q/k -> Q/K [b][h][n][64]      (1 KB contiguous per wave instruction)
//   v   -> Vt  [b][h][d][2048]    (transpose via scalar LDS column reads)
// ---------------------------------------------------------------------------
__global__ __launch_bounds__(256) void gemm_qkv(const unsigned short* __restrict__ A,
                                                const unsigned short* __restrict__ B,
                                                unsigned short* __restrict__ Qm,
                                                unsigned short* __restrict__ Km,
                                                unsigned short* __restrict__ Vtm) {
    const int K = 1024;
    __shared__ unsigned short base[4 * 64 * 72];               // 36.9 KB
    unsigned short* Alf = base;                                // 128x64
    unsigned short* Blf = base + 8192;                         // 128x64
    unsigned short (*Al)[64] = (unsigned short(*)[64])Alf;
    unsigned short (*Bl)[64] = (unsigned short(*)[64])Blf;
    const int tid  = threadIdx.x;
    const int lane = tid & 63;
    const int qd   = lane >> 4;
    const int cc   = lane & 15;
    const int wave = tid >> 6;
    const int wr   = wave >> 1, wc = wave & 1;
    const int m0   = blockIdx.y * 128, n0 = blockIdx.x * 128;

    f32x4 acc[4][4];
#pragma unroll
    for (int i = 0; i < 4; i++)
#pragma unroll
        for (int j = 0; j < 4; j++) acc[i][j] = (f32x4){0.f, 0.f, 0.f, 0.f};

    for (int k0 = 0; k0 < K; k0 += 64) {
#pragma unroll
        for (int t = 0; t < 4; t++) {
            int idx = t * 256 + tid;                 // 0..1023
            int row = idx >> 3, sg = (idx & 7) ^ (row & 7);
            GLD_TO_LDS(A + (size_t)(m0 + row) * K + k0 + sg * 8, Alf + idx * 8);
            GLD_TO_LDS(B + (size_t)(n0 + row) * K + k0 + sg * 8, Blf + idx * 8);
        }
        __syncthreads();
#pragma unroll
        for (int ks = 0; ks < 64; ks += 32) {
            const int s4 = ks >> 3;
            s16x8 af[4], bf[4];
#pragma unroll
            for (int i = 0; i < 4; i++) {
                int r = wr * 64 + i * 16 + cc;
                af[i] = *(const s16x8*)&Al[r][((s4 + qd) ^ (r & 7)) * 8];
            }
#pragma unroll
            for (int j = 0; j < 4; j++) {
                int r = wc * 64 + j * 16 + cc;
                bf[j] = *(const s16x8*)&Bl[r][((s4 + qd) ^ (r & 7)) * 8];
            }
#pragma unroll
            for (int i = 0; i < 4; i++)
#pragma unroll
                for (int j = 0; j < 4; j++)
                    acc[i][j] = MFMA_BF16(af[i], bf[j], acc[i][j]);
        }
        __syncthreads();
    }

    // ---- fused epilogue ----
    const int sec = n0 >> 10;                  // 0=q, 1=k, 2=v
    const int b   = m0 >> 11;
    const int h0  = (n0 & 1023) >> 6;          // first of the tile's 2 heads
    const int nb  = m0 & 2047;                 // n offset of tile row 0
    unsigned short* Wb = base + wave * 4608;   // this wave's 64x72 buffer

    if (sec < 2) {
        unsigned short* dst = sec ? Km : Qm;
        // RoPE on fp32 acc (R5-verified math), write bf16 to bounce buffer
        // with XOR seg-swizzle (slot = seg ^ (row&7)) for conflict-free reads.
        const float if0 = exp2f(-0.34375f * (float)cc);          // freq(cc)
        const float if1 = exp2f(-0.34375f * (float)(16 + cc));   // freq(16+cc)
#pragma unroll
        for (int i = 0; i < 4; i++)
#pragma unroll
            for (int r = 0; r < 4; r++) {
                int rl = i * 16 + qd * 4 + r;              // row in quadrant
                float fn = (float)(nb + wr * 64 + rl);
                float t0 = fn * if0, t1 = fn * if1;
                float c0 = cosf(t0), s0 = sinf(t0);
                float c1 = cosf(t1), s1 = sinf(t1);
#pragma unroll
                for (int j = 0; j < 4; j++) {
                    float cv = (j & 1) ? c1 : c0;
                    float sv = (j & 1) ? s1 : s0;
                    float pr = acc[i][j ^ 2][r] * sv;      // rotate_half partner
                    float v  = (j & 2) ? fmaf(acc[i][j][r], cv, pr)
                                       : fmaf(acc[i][j][r], cv, -pr);
                    int slot = (j * 2 + (cc >> 3)) ^ (rl & 7);
                    Wb[rl * 72 + slot * 8 + (cc & 7)] = f2bf(v);
                }
            }
        __syncthreads();
        // dense stores: lane-consecutive chunks, 1 KB contiguous / wave instr
        const int l128 = tid & 127, p = tid >> 7;          // p = head in tile
        const size_t hb = ((size_t)(b * 16 + h0 + p) * 2048 + nb) * 64;
#pragma unroll
        for (int sgi = 0; sgi < 8; sgi++) {
            int rr = sgi * 16 + (l128 >> 3), s = l128 & 7;
            const unsigned short* src = base + ((rr >> 6) * 2 + p) * 4608
                                        + (rr & 63) * 72 + ((s ^ (rr & 7)) * 8);
            *(u16x8*)&dst[hb + (size_t)rr * 64 + s * 8] = *(const u16x8*)src;
        }
    } else {
        // V: bounce (no RoPE, no swizzle), then transposed dense stores to Vt
#pragma unroll
        for (int i = 0; i < 4; i++)
#pragma unroll
            for (int j = 0; j < 4; j++)
#pragma unroll
                for (int r = 0; r < 4; r++)
                    Wb[(i * 16 + qd * 4 + r) * 72 + j * 16 + cc] =
                        f2bf(acc[i][j][r]);
        __syncthreads();
        const int dd = tid >> 1, half = tid & 1;           // d-row, n-half
        const int p = dd >> 6, d = dd & 63;
        const unsigned short* src = base + (half * 2 + p) * 4608 + d;
        size_t gb = ((size_t)(b * 16 + h0 + p) * 64 + d) * 2048 + nb + half * 64;
#pragma unroll
        for (int c = 0; c < 8; c++) {
            u16x8 ov;
#pragma unroll
            for (int t = 0; t < 8; t++) ov[t] = src[(c * 8 + t) * 72];
            *(u16x8*)&Vtm[gb + c * 8] = ov;
        }
    }
}

// ---------------------------------------------------------------------------
// Flash attention (R8 verbatim, measured 73.2 us): 128-row q-tile, 512
// threads = 8 waves x 16 q-rows.  K+V dbuf DMA staging, S^T orientation,
// softmax-lite (no running max), l via MFMA-ones.  K-tiles of 64.
// ---------------------------------------------------------------------------
__global__ __launch_bounds__(512, 4) void flash_attn(const unsigned short* __restrict__ Q,
                                                     const unsigned short* __restrict__ Kg,
                                                     const unsigned short* __restrict__ Vt,
                                                     const float* __restrict__ fb,
                                                     unsigned short* __restrict__ Og) {
    const int N = 2048, H = 16, D = 64;
    const float SCL = 0.18033688f;             // 0.125 * log2(e)
    __shared__ unsigned short Kl0[64][64], Kl1[64][64];   // [key][d] swizzled
    __shared__ unsigned short Vl0[64][64], Vl1[64][64];   // [d][key] swizzled
    __shared__ unsigned short Pl[8][16][76];   // [wave][query][key], stride 76
    const int tid  = threadIdx.x;
    const int lane = tid & 63;
    const int wave = tid >> 6;                 // 0..7
    const int qd   = lane >> 4;
    const int cc   = lane & 15;
    const int qt = blockIdx.x, h = blockIdx.y, b = blockIdx.z;
    const int q0 = qt * 128;
    const size_t bh = (size_t)b * H + h;

    // Q B-frags: B[n=q=lane&15][k=d=quad*8+j]; wave covers 16 queries
    const unsigned short* Qb = Q + (bh * N + q0 + wave * 16 + cc) * D;
    s16x8 qf0 = *(const s16x8*)(Qb + qd * 8);
    s16x8 qf1 = *(const s16x8*)(Qb + 32 + qd * 8);

    // constant ones B-fragment (bf16 1.0 = 0x3F80) for l = P @ 1
    s16x8 ones;
#pragma unroll
    for (int j = 0; j < 8; j++) ones[j] = (short)0x3F80;

    f32x4 o[4], lacc;
    lacc = (f32x4){0.f, 0.f, 0.f, 0.f};
#pragma unroll
    for (int db = 0; db < 4; db++) o[db] = (f32x4){0.f, 0.f, 0.f, 0.f};

    const unsigned short* Kbase = Kg + bh * N * D;
    const unsigned short* Vbase = Vt + bh * D * N;
    const float* fbase = fb + (size_t)b * N;
    const int row_s = tid >> 3, sg_s = (tid & 7) ^ ((tid >> 3) & 7);   // 512 thr = full tile

    auto issue = [&](int k0, unsigned short* Kb, unsigned short* Vb) {
        GLD_TO_LDS(Kbase + (size_t)(k0 + row_s) * D + sg_s * 8, Kb + tid * 8);
        GLD_TO_LDS(Vbase + (size_t)row_s * N + k0 + sg_s * 8,   Vb + tid * 8);
    };

    auto compute = [&](int k0, const unsigned short (*Kb)[64], const unsigned short (*Vb)[64]) {
        f32x4 fbv[4];
#pragma unroll
        for (int sub = 0; sub < 4; sub++)
            fbv[sub] = *(const f32x4*)(fbase + k0 + sub * 16 + qd * 4);

        // S^T = K Q^T, softmax-lite, pack pairs -> Pl
#pragma unroll
        for (int sub = 0; sub < 4; sub++) {
            int kr = sub * 16 + cc;
            s16x8 kf0 = *(const s16x8*)&Kb[kr][((0 + qd) ^ (kr & 7)) * 8];
            s16x8 kf1 = *(const s16x8*)&Kb[kr][((4 + qd) ^ (kr & 7)) * 8];
            f32x4 s = (f32x4){0.f, 0.f, 0.f, 0.f};
            s = MFMA_BF16(kf0, qf0, s);
            s = MFMA_BF16(kf1, qf1, s);
            float p0 = exp2f(fmaf(s[0], SCL, fbv[sub][0]));
            float p1 = exp2f(fmaf(s[1], SCL, fbv[sub][1]));
            float p2 = exp2f(fmaf(s[2], SCL, fbv[sub][2]));
            float p3 = exp2f(fmaf(s[3], SCL, fbv[sub][3]));
            unsigned int d0 = __builtin_amdgcn_perm(
                __builtin_bit_cast(unsigned int, p1),
                __builtin_bit_cast(unsigned int, p0), 0x07060302u);
            unsigned int d1 = __builtin_amdgcn_perm(
                __builtin_bit_cast(unsigned int, p3),
                __builtin_bit_cast(unsigned int, p2), 0x07060302u);
            unsigned long long w = ((unsigned long long)d1 << 32) | d0;
            *(unsigned long long*)&Pl[wave][cc][sub * 16 + qd * 4] = w;
        }

        // O += P V ; l += P @ 1  (A-frag P[m=q][k=key] contiguous reads)
#pragma unroll
        for (int ks = 0; ks < 2; ks++) {
            s16x8 pf = *(const s16x8*)&Pl[wave][cc][ks * 32 + qd * 8];
            lacc = MFMA_BF16(pf, ones, lacc);
#pragma unroll
            for (int db = 0; db < 4; db++) {
                int vr = db * 16 + cc;
                s16x8 vfl = *(const s16x8*)&Vb[vr][((ks * 4 + qd) ^ (vr & 7)) * 8];
                o[db] = MFMA_BF16(pf, vfl, o[db]);
            }
        }
    };

    issue(0, &Kl0[0][0], &Vl0[0][0]);
    __syncthreads();
    for (int it = 0; it < 32; it += 2) {
        int k0 = it * 64;
        if (it + 1 < 32) issue(k0 + 64, &Kl1[0][0], &Vl1[0][0]);
        compute(k0, Kl0, Vl0);
        __syncthreads();
        if (it + 2 < 32) issue(k0 + 128, &Kl0[0][0], &Vl0[0][0]);
        compute(k0 + 64, Kl1, Vl1);
        __syncthreads();
    }

    // epilogue: lacc rows == o rows (query = qd*4 + r)
    float linv[4];
#pragma unroll
    for (int r = 0; r < 4; r++) linv[r] = 1.0f / lacc[r];
#pragma unroll
    for (int db = 0; db < 4; db++)
#pragma unroll
        for (int r = 0; r < 4; r++) {
            int n = q0 + wave * 16 + qd * 4 + r;
            Og[((size_t)b * N + n) * 1024 + h * 64 + db * 16 + cc] =
                f2bf(o[db][r] * linv[r]);
        }
}

// ---------------------------------------------------------------------------
// Projection GEMM: out[4096,1024] = attno[4096,1024] @ w_proj^T + bias, fp32.
// 128x64 tile -> 512 blocks = 2 blocks/CU.
// ---------------------------------------------------------------------------
__global__ __launch_bounds__(256) void gemm_proj(const unsigned short* __restrict__ A,
                                                 const unsigned short* __restrict__ B,
                                                 float* __restrict__ C,
                                                 const float* __restrict__ bias) {
    const int NN = 1024, K = 1024;
    __shared__ unsigned short Al[128][64];
    __shared__ unsigned short Bl[64][64];
    const int tid  = threadIdx.x;
    const int lane = tid & 63;
    const int qd   = lane >> 4;
    const int cc   = lane & 15;
    const int wave = tid >> 6;
    const int wr   = wave >> 1, wc = wave & 1;
    const int m0   = blockIdx.y * 128, n0 = blockIdx.x * 64;
    unsigned short* Alf = &Al[0][0];
    unsigned short* Blf = &Bl[0][0];

    f32x4 acc[4][2];
#pragma unroll
    for (int i = 0; i < 4; i++)
#pragma unroll
        for (int j = 0; j < 2; j++) acc[i][j] = (f32x4){0.f, 0.f, 0.f, 0.f};

    for (int k0 = 0; k0 < K; k0 += 64) {
#pragma unroll
        for (int t = 0; t < 4; t++) {
            int idx = t * 256 + tid;
            int row = idx >> 3, sg = (idx & 7) ^ (row & 7);
            GLD_TO_LDS(A + (size_t)(m0 + row) * K + k0 + sg * 8, Alf + idx * 8);
        }
#pragma unroll
        for (int t = 0; t < 2; t++) {
            int idx = t * 256 + tid;
            int row = idx >> 3, sg = (idx & 7) ^ (row & 7);
            GLD_TO_LDS(B + (size_t)(n0 + row) * K + k0 + sg * 8, Blf + idx * 8);
        }
        __syncthreads();
#pragma unroll
        for (int ks = 0; ks < 64; ks += 32) {
            const int s4 = ks >> 3;
            s16x8 af[4], bf[2];
#pragma unroll
            for (int i = 0; i < 4; i++) {
                int r = wr * 64 + i * 16 + cc;
                af[i] = *(const s16x8*)&Al[r][((s4 + qd) ^ (r & 7)) * 8];
            }
#pragma unroll
            for (int j = 0; j < 2; j++) {
                int r = wc * 32 + j * 16 + cc;
                bf[j] = *(const s16x8*)&Bl[r][((s4 + qd) ^ (r & 7)) * 8];
            }
#pragma unroll
            for (int i = 0; i < 4; i++)
#pragma unroll
                for (int j = 0; j < 2; j++)
                    acc[i][j] = MFMA_BF16(af[i], bf[j], acc[i][j]);
        }
        __syncthreads();
    }
#pragma unroll
    for (int i = 0; i < 4; i++)
#pragma unroll
        for (int j = 0; j < 2; j++)
#pragma unroll
            for (int r = 0; r < 4; r++) {
                int row = m0 + wr * 64 + i * 16 + qd * 4 + r;
                int col = n0 + wc * 32 + j * 16 + cc;
                C[(size_t)row * NN + col] = acc[i][j][r] + bias[col];
            }
}

// ---------------------------------------------------------------------------
extern "C" void kernel_launch(void* const* d_in, const int* in_sizes, int n_in,
                              void* d_out, int out_size, void* d_ws, size_t ws_size,
                              hipStream_t stream) {
    const float* x      = (const float*)d_in[0];
    const float* w_qkv  = (const float*)d_in[1];
    const float* w_proj = (const float*)d_in[2];
    const float* b_proj = (const float*)d_in[3];
    const int*   mask   = (const int*)d_in[4];
    float* out = (float*)d_out;

    // workspace layout (bf16 elements), ~48 MB
    unsigned short* ws     = (unsigned short*)d_ws;
    unsigned short* xb     = ws;                                  // 4096*1024
    unsigned short* wqkvb  = xb     + (size_t)4096 * 1024;        // 3072*1024
    unsigned short* wprojb = wqkvb  + (size_t)3072 * 1024;        // 1024*1024
    unsigned short* Qm     = wprojb + (size_t)1024 * 1024;        // 32*2048*64
    unsigned short* Km     = Qm     + (size_t)32 * 2048 * 64;
    unsigned short* Vtm    = Km     + (size_t)32 * 2048 * 64;
    unsigned short* attno  = Vtm    + (size_t)32 * 2048 * 64;     // 4096*1024
    float*          fbias  = (float*)(attno + (size_t)4096 * 1024); // 2*2048 f32

    // converts + mask bias, one launch
    prep<<<8208, 256, 0, stream>>>(x, w_qkv, w_proj, mask, xb, wqkvb, wprojb, fbias);
    // QKV GEMM + fused RoPE/scatter (dense LDS-bounced stores)
    gemm_qkv<<<dim3(24, 32), 256, 0, stream>>>(xb, wqkvb, Qm, Km, Vtm);
    // attention: R8 shape (128-row q-tiles, 512 threads, K+V dbuf)
    flash_attn<<<dim3(16, 16, 2), 512, 0, stream>>>(Qm, Km, Vtm, fbias, attno);
    // out = attn_out @ w_proj^T + b_proj
    gemm_proj<<<dim3(16, 32), 256, 0, stream>>>(attno, wprojb, out, b_proj);
}